// Round 1
// baseline (184.300 us; speedup 1.0000x reference)
//
#include <hip/hip_runtime.h>
#include <cmath>

#define NLOD 10

// Codebook sizes are certain at compile time: min(lod^2, 1024).
// (The only float-boundary-uncertain LOD is #9: res 64 vs 65, but
// min(64^2,1024) == min(65^2,1024) == 1024, so sizes are fixed.)
static constexpr int SIZES[NLOD]     = {49, 64, 121, 196, 324, 529, 900, 1024, 1024, 1024};
static constexpr int ENTRY_OFS[NLOD] = {0, 49, 113, 234, 430, 754, 1283, 2183, 3207, 4231};
static constexpr int TOTAL_ENTRIES   = 5255;   // sum of SIZES
// LDS: 5255 entries * 3 floats * 4 B = 63060 B  (< 64 KB static limit)

struct ResArr { int r[NLOD]; };

template <int SIZE>
__device__ __forceinline__ void level_accum(const float* __restrict__ cb, int res,
                                            float px, float py, float pz,
                                            float& a0, float& a1, float& a2)
{
    const float s   = (float)(res - 1);
    const float fhi = (float)(res - 2);

    float fx = px * s, fy = py * s, fz = pz * s;

    // x0 = clip(floor(x), 0, res-2); w = x - x0   (matches reference exactly)
    float ffx = fminf(fmaxf(floorf(fx), 0.0f), fhi);
    float ffy = fminf(fmaxf(floorf(fy), 0.0f), fhi);
    float ffz = fminf(fmaxf(floorf(fz), 0.0f), fhi);
    float wx = fx - ffx, wy = fy - ffy, wz = fz - ffz;

    unsigned ux = (unsigned)(int)ffx;
    unsigned uy = (unsigned)(int)ffy;
    unsigned uz = (unsigned)(int)ffz;

    // Incremental hash terms: h = (x*1) ^ (y*P1) ^ (z*P2)
    const unsigned P1 = 2654435761u, P2 = 805459861u;
    unsigned hx0 = ux;
    unsigned hx1 = ux + 1u;
    unsigned hy0 = uy * P1;
    unsigned hy1 = hy0 + P1;
    unsigned hz0 = uz * P2;
    unsigned hz1 = hz0 + P2;

    float wx0 = 1.0f - wx, wy0 = 1.0f - wy, wz0 = 1.0f - wz;
    // factorized corner weights
    float w00 = wx0 * wy0, w01 = wx0 * wy, w10 = wx * wy0, w11 = wx * wy;

    float l0 = 0.0f, l1 = 0.0f, l2 = 0.0f;

    auto corner = [&](unsigned hx, unsigned hy, unsigned hz, float wt) {
        unsigned idx = (hx ^ hy ^ hz) % (unsigned)SIZE;  // constexpr divisor -> magic mul / AND
        const float* f = cb + idx * 3;
        l0 = fmaf(f[0], wt, l0);
        l1 = fmaf(f[1], wt, l1);
        l2 = fmaf(f[2], wt, l2);
    };

    // reference OFFSETS order: (i,j,k) for i in(0,1) j in(0,1) k in(0,1)
    corner(hx0, hy0, hz0, w00 * wz0);
    corner(hx0, hy0, hz1, w00 * wz);
    corner(hx0, hy1, hz0, w01 * wz0);
    corner(hx0, hy1, hz1, w01 * wz);
    corner(hx1, hy0, hz0, w10 * wz0);
    corner(hx1, hy0, hz1, w10 * wz);
    corner(hx1, hy1, hz0, w11 * wz0);
    corner(hx1, hy1, hz1, w11 * wz);

    a0 += l0; a1 += l1; a2 += l2;   // per-level partial then add (matches ref sum structure)
}

__global__ __launch_bounds__(512, 4)
void hashgrid_kernel(const float* __restrict__ pts,
                     const float* __restrict__ c0, const float* __restrict__ c1,
                     const float* __restrict__ c2, const float* __restrict__ c3,
                     const float* __restrict__ c4, const float* __restrict__ c5,
                     const float* __restrict__ c6, const float* __restrict__ c7,
                     const float* __restrict__ c8, const float* __restrict__ c9,
                     float* __restrict__ out, int npts, ResArr res)
{
    __shared__ float cb[TOTAL_ENTRIES * 3];

    // Stage all codebooks into LDS (coalesced, once per block)
    {
        const float* srcs[NLOD] = {c0, c1, c2, c3, c4, c5, c6, c7, c8, c9};
#pragma unroll
        for (int L = 0; L < NLOD; ++L) {
            const int n3   = SIZES[L] * 3;
            const int base = ENTRY_OFS[L] * 3;
            for (int i = threadIdx.x; i < n3; i += blockDim.x)
                cb[base + i] = srcs[L][i];
        }
    }
    __syncthreads();

    const int stride = gridDim.x * blockDim.x;
    for (int n = blockIdx.x * blockDim.x + threadIdx.x; n < npts; n += stride) {
        float px = pts[n * 3 + 0];
        float py = pts[n * 3 + 1];
        float pz = pts[n * 3 + 2];

        float a0 = 0.0f, a1 = 0.0f, a2 = 0.0f;

        level_accum<  49>(cb + ENTRY_OFS[0] * 3, res.r[0], px, py, pz, a0, a1, a2);
        level_accum<  64>(cb + ENTRY_OFS[1] * 3, res.r[1], px, py, pz, a0, a1, a2);
        level_accum< 121>(cb + ENTRY_OFS[2] * 3, res.r[2], px, py, pz, a0, a1, a2);
        level_accum< 196>(cb + ENTRY_OFS[3] * 3, res.r[3], px, py, pz, a0, a1, a2);
        level_accum< 324>(cb + ENTRY_OFS[4] * 3, res.r[4], px, py, pz, a0, a1, a2);
        level_accum< 529>(cb + ENTRY_OFS[5] * 3, res.r[5], px, py, pz, a0, a1, a2);
        level_accum< 900>(cb + ENTRY_OFS[6] * 3, res.r[6], px, py, pz, a0, a1, a2);
        level_accum<1024>(cb + ENTRY_OFS[7] * 3, res.r[7], px, py, pz, a0, a1, a2);
        level_accum<1024>(cb + ENTRY_OFS[8] * 3, res.r[8], px, py, pz, a0, a1, a2);
        level_accum<1024>(cb + ENTRY_OFS[9] * 3, res.r[9], px, py, pz, a0, a1, a2);

        out[n * 3 + 0] = a0;
        out[n * 3 + 1] = a1;
        out[n * 3 + 2] = a2;
    }
}

extern "C" void kernel_launch(void* const* d_in, const int* in_sizes, int n_in,
                              void* d_out, int out_size, void* d_ws, size_t ws_size,
                              hipStream_t stream)
{
    const float* pts = (const float*)d_in[0];
    const int npts = in_sizes[0] / 3;

    // Replicate numpy's exact double-precision LOD computation (glibc libm).
    // LOD 9 sits at 6*b^9 == 64.0 +/- ~1e-14: floor() is boundary-sensitive,
    // so compute with the same op sequence instead of hardcoding.
    ResArr ra;
    const double b = exp((log(64.0) - log(6.0)) / 9.0);
    for (int l = 0; l < NLOD; ++l)
        ra.r[l] = (int)(1.0 + floor(6.0 * pow(b, (double)l)));

    hashgrid_kernel<<<dim3(512), dim3(512), 0, stream>>>(
        pts,
        (const float*)d_in[1], (const float*)d_in[2], (const float*)d_in[3],
        (const float*)d_in[4], (const float*)d_in[5], (const float*)d_in[6],
        (const float*)d_in[7], (const float*)d_in[8], (const float*)d_in[9],
        (const float*)d_in[10],
        (float*)d_out, npts, ra);
}

// Round 2
// 147.255 us; speedup vs baseline: 1.2516x; 1.2516x over previous
//
#include <hip/hip_runtime.h>
#include <hip/hip_fp16.h>
#include <cmath>

#define NLOD 10

// Codebook sizes are certain at compile time: min(lod^2, 1024).
// (LOD 9 is float-boundary-uncertain between res 64/65, but
// min(64^2,1024) == min(65^2,1024) == 1024, so sizes are fixed.)
static constexpr int SIZES[NLOD]     = {49, 64, 121, 196, 324, 529, 900, 1024, 1024, 1024};
static constexpr int ENTRY_OFS[NLOD] = {0, 49, 113, 234, 430, 754, 1283, 2183, 3207, 4231};
static constexpr int TOTAL_ENTRIES   = 5255;
// LDS: 5255 entries * 4 halves * 2 B = 42040 B  -> 3 blocks/CU (160 KB)

struct ResArr { int r[NLOD]; };

template <int SIZE>
__device__ __forceinline__ void level_accum(const __half* __restrict__ cb, int res,
                                            float px, float py, float pz,
                                            float& a0, float& a1, float& a2)
{
    const float s   = (float)(res - 1);
    const float fhi = (float)(res - 2);

    float fx = px * s, fy = py * s, fz = pz * s;

    // x0 = clip(floor(x), 0, res-2); w = x - x0   (matches reference exactly)
    float ffx = fminf(fmaxf(floorf(fx), 0.0f), fhi);
    float ffy = fminf(fmaxf(floorf(fy), 0.0f), fhi);
    float ffz = fminf(fmaxf(floorf(fz), 0.0f), fhi);
    float wx = fx - ffx, wy = fy - ffy, wz = fz - ffz;

    unsigned ux = (unsigned)(int)ffx;
    unsigned uy = (unsigned)(int)ffy;
    unsigned uz = (unsigned)(int)ffz;

    // Incremental hash terms: h = (x*1) ^ (y*P1) ^ (z*P2)
    const unsigned P1 = 2654435761u, P2 = 805459861u;
    unsigned hx0 = ux;
    unsigned hx1 = ux + 1u;
    unsigned hy0 = uy * P1;
    unsigned hy1 = hy0 + P1;
    unsigned hz0 = uz * P2;
    unsigned hz1 = hz0 + P2;

    // precombine x^y hash terms (saves 4 xors vs per-corner)
    unsigned hxy00 = hx0 ^ hy0, hxy01 = hx0 ^ hy1;
    unsigned hxy10 = hx1 ^ hy0, hxy11 = hx1 ^ hy1;

    float wx0 = 1.0f - wx, wy0 = 1.0f - wy, wz0 = 1.0f - wz;
    float w00 = wx0 * wy0, w01 = wx0 * wy, w10 = wx * wy0, w11 = wx * wy;

    float l0 = 0.0f, l1 = 0.0f, l2 = 0.0f;

    auto corner = [&](unsigned hxy, unsigned hz, float wt) {
        unsigned idx = (hxy ^ hz) % (unsigned)SIZE;  // constexpr divisor -> magic mul / AND
        // one aligned 8-byte LDS read: f16 x {f0,f1,f2,pad}
        float2 raw = reinterpret_cast<const float2*>(cb)[idx];
        __half2 v01 = *reinterpret_cast<const __half2*>(&raw.x);
        __half2 v2x = *reinterpret_cast<const __half2*>(&raw.y);
        float2 f01 = __half22float2(v01);
        float  f2  = __half2float(__low2half(v2x));
        l0 = fmaf(f01.x, wt, l0);
        l1 = fmaf(f01.y, wt, l1);
        l2 = fmaf(f2,    wt, l2);
    };

    // reference OFFSETS order: (i,j,k) for i in(0,1) j in(0,1) k in(0,1)
    corner(hxy00, hz0, w00 * wz0);
    corner(hxy00, hz1, w00 * wz);
    corner(hxy01, hz0, w01 * wz0);
    corner(hxy01, hz1, w01 * wz);
    corner(hxy10, hz0, w10 * wz0);
    corner(hxy10, hz1, w10 * wz);
    corner(hxy11, hz0, w11 * wz0);
    corner(hxy11, hz1, w11 * wz);

    a0 += l0; a1 += l1; a2 += l2;
}

__global__ __launch_bounds__(512, 6)
void hashgrid_kernel(const float* __restrict__ pts,
                     const float* __restrict__ c0, const float* __restrict__ c1,
                     const float* __restrict__ c2, const float* __restrict__ c3,
                     const float* __restrict__ c4, const float* __restrict__ c5,
                     const float* __restrict__ c6, const float* __restrict__ c7,
                     const float* __restrict__ c8, const float* __restrict__ c9,
                     float* __restrict__ out, int npts, ResArr res)
{
    __shared__ __half cbh[TOTAL_ENTRIES * 4];   // 42040 B

    // Stage + compress codebooks into LDS (once per block)
    {
        const float* srcs[NLOD] = {c0, c1, c2, c3, c4, c5, c6, c7, c8, c9};
#pragma unroll
        for (int L = 0; L < NLOD; ++L) {
            for (int e = threadIdx.x; e < SIZES[L]; e += blockDim.x) {
                const float* s = srcs[L] + e * 3;
                __half2* d = reinterpret_cast<__half2*>(cbh + (ENTRY_OFS[L] + e) * 4);
                d[0] = __floats2half2_rn(s[0], s[1]);
                d[1] = __floats2half2_rn(s[2], 0.0f);
            }
        }
    }
    __syncthreads();

    const int stride = gridDim.x * blockDim.x;
    for (int n = blockIdx.x * blockDim.x + threadIdx.x; n < npts; n += stride) {
        float px = pts[n * 3 + 0];
        float py = pts[n * 3 + 1];
        float pz = pts[n * 3 + 2];

        float a0 = 0.0f, a1 = 0.0f, a2 = 0.0f;

        level_accum<  49>(cbh + ENTRY_OFS[0] * 4, res.r[0], px, py, pz, a0, a1, a2);
        level_accum<  64>(cbh + ENTRY_OFS[1] * 4, res.r[1], px, py, pz, a0, a1, a2);
        level_accum< 121>(cbh + ENTRY_OFS[2] * 4, res.r[2], px, py, pz, a0, a1, a2);
        level_accum< 196>(cbh + ENTRY_OFS[3] * 4, res.r[3], px, py, pz, a0, a1, a2);
        level_accum< 324>(cbh + ENTRY_OFS[4] * 4, res.r[4], px, py, pz, a0, a1, a2);
        level_accum< 529>(cbh + ENTRY_OFS[5] * 4, res.r[5], px, py, pz, a0, a1, a2);
        level_accum< 900>(cbh + ENTRY_OFS[6] * 4, res.r[6], px, py, pz, a0, a1, a2);
        level_accum<1024>(cbh + ENTRY_OFS[7] * 4, res.r[7], px, py, pz, a0, a1, a2);
        level_accum<1024>(cbh + ENTRY_OFS[8] * 4, res.r[8], px, py, pz, a0, a1, a2);
        level_accum<1024>(cbh + ENTRY_OFS[9] * 4, res.r[9], px, py, pz, a0, a1, a2);

        out[n * 3 + 0] = a0;
        out[n * 3 + 1] = a1;
        out[n * 3 + 2] = a2;
    }
}

extern "C" void kernel_launch(void* const* d_in, const int* in_sizes, int n_in,
                              void* d_out, int out_size, void* d_ws, size_t ws_size,
                              hipStream_t stream)
{
    const float* pts = (const float*)d_in[0];
    const int npts = in_sizes[0] / 3;

    // Replicate numpy's exact double-precision LOD computation (glibc libm).
    ResArr ra;
    const double b = exp((log(64.0) - log(6.0)) / 9.0);
    for (int l = 0; l < NLOD; ++l)
        ra.r[l] = (int)(1.0 + floor(6.0 * pow(b, (double)l)));

    hashgrid_kernel<<<dim3(768), dim3(512), 0, stream>>>(
        pts,
        (const float*)d_in[1], (const float*)d_in[2], (const float*)d_in[3],
        (const float*)d_in[4], (const float*)d_in[5], (const float*)d_in[6],
        (const float*)d_in[7], (const float*)d_in[8], (const float*)d_in[9],
        (const float*)d_in[10],
        (float*)d_out, npts, ra);
}

// Round 3
// 142.811 us; speedup vs baseline: 1.2905x; 1.0311x over previous
//
#include <hip/hip_runtime.h>
#include <hip/hip_fp16.h>
#include <cmath>

#define NLOD 10

// Codebook sizes are certain at compile time: min(lod^2, 1024).
// (LOD 9 is float-boundary-uncertain between res 64/65, but
// min(64^2,1024) == min(65^2,1024) == 1024, so sizes are fixed.)
static constexpr int SIZES[NLOD]     = {49, 64, 121, 196, 324, 529, 900, 1024, 1024, 1024};
static constexpr int ENTRY_OFS[NLOD] = {0, 49, 113, 234, 430, 754, 1283, 2183, 3207, 4231};
static constexpr int TOTAL_ENTRIES   = 5255;
// LDS: 5255 entries * 8 B = 42040 B -> two 1024-thread blocks/CU (84 KB of 160 KB)

struct ResArr { int r[NLOD]; };

template <int SIZE>
__device__ __forceinline__ void level_accum(const __half* __restrict__ cb, int res,
                                            float px, float py, float pz,
                                            float& a0, float& a1, float& a2)
{
    const float s   = (float)(res - 1);
    const float fhi = (float)(res - 2);

    float fx = px * s, fy = py * s, fz = pz * s;

    // x0 = clip(floor(x), 0, res-2); w = x - x0   (matches reference exactly)
    float ffx = fminf(fmaxf(floorf(fx), 0.0f), fhi);
    float ffy = fminf(fmaxf(floorf(fy), 0.0f), fhi);
    float ffz = fminf(fmaxf(floorf(fz), 0.0f), fhi);
    float wx = fx - ffx, wy = fy - ffy, wz = fz - ffz;

    unsigned ux = (unsigned)(int)ffx;
    unsigned uy = (unsigned)(int)ffy;
    unsigned uz = (unsigned)(int)ffz;

    // Incremental hash terms: h = (x*1) ^ (y*P1) ^ (z*P2)
    const unsigned P1 = 2654435761u, P2 = 805459861u;
    unsigned hx0 = ux;
    unsigned hx1 = ux + 1u;
    unsigned hy0 = uy * P1;
    unsigned hy1 = hy0 + P1;
    unsigned hz0 = uz * P2;
    unsigned hz1 = hz0 + P2;

    unsigned hxy00 = hx0 ^ hy0, hxy01 = hx0 ^ hy1;
    unsigned hxy10 = hx1 ^ hy0, hxy11 = hx1 ^ hy1;

    float wx0 = 1.0f - wx, wy0 = 1.0f - wy, wz0 = 1.0f - wz;
    float w00 = wx0 * wy0, w01 = wx0 * wy, w10 = wx * wy0, w11 = wx * wy;

    // fma_mix-friendly corner: single ds_read_b64, then three
    // fma(fpext(f16), f32, f32) -> v_fma_mix_f32 (no separate cvt).
    auto corner = [&](unsigned h, float wt) {
        unsigned idx = h % (unsigned)SIZE;  // constexpr divisor -> magic mul / AND
        uint2 raw = reinterpret_cast<const uint2*>(cb)[idx];
        __half2 p01 = *reinterpret_cast<const __half2*>(&raw.x);
        __half2 p2x = *reinterpret_cast<const __half2*>(&raw.y);
        a0 = fmaf(__half2float(__low2half(p01)),  wt, a0);
        a1 = fmaf(__half2float(__high2half(p01)), wt, a1);
        a2 = fmaf(__half2float(__low2half(p2x)),  wt, a2);
    };

    // reference OFFSETS order: (i,j,k) for i in(0,1) j in(0,1) k in(0,1)
    corner(hxy00 ^ hz0, w00 * wz0);
    corner(hxy00 ^ hz1, w00 * wz);
    corner(hxy01 ^ hz0, w01 * wz0);
    corner(hxy01 ^ hz1, w01 * wz);
    corner(hxy10 ^ hz0, w10 * wz0);
    corner(hxy10 ^ hz1, w10 * wz);
    corner(hxy11 ^ hz0, w11 * wz0);
    corner(hxy11 ^ hz1, w11 * wz);
}

__global__ __launch_bounds__(1024, 8)
void hashgrid_kernel(const float* __restrict__ pts,
                     const float* __restrict__ c0, const float* __restrict__ c1,
                     const float* __restrict__ c2, const float* __restrict__ c3,
                     const float* __restrict__ c4, const float* __restrict__ c5,
                     const float* __restrict__ c6, const float* __restrict__ c7,
                     const float* __restrict__ c8, const float* __restrict__ c9,
                     float* __restrict__ out, int npts, ResArr res)
{
    __shared__ __half cbh[TOTAL_ENTRIES * 4];   // 42040 B

    // Stage + compress codebooks into LDS (once per block)
    {
        const float* srcs[NLOD] = {c0, c1, c2, c3, c4, c5, c6, c7, c8, c9};
#pragma unroll
        for (int L = 0; L < NLOD; ++L) {
            for (int e = threadIdx.x; e < SIZES[L]; e += blockDim.x) {
                const float* s = srcs[L] + e * 3;
                __half2* d = reinterpret_cast<__half2*>(cbh + (ENTRY_OFS[L] + e) * 4);
                d[0] = __floats2half2_rn(s[0], s[1]);
                d[1] = __floats2half2_rn(s[2], 0.0f);
            }
        }
    }
    __syncthreads();

    const int stride = gridDim.x * blockDim.x;
    for (int n = blockIdx.x * blockDim.x + threadIdx.x; n < npts; n += stride) {
        float px = pts[n * 3 + 0];
        float py = pts[n * 3 + 1];
        float pz = pts[n * 3 + 2];

        float a0 = 0.0f, a1 = 0.0f, a2 = 0.0f;

        level_accum<  49>(cbh + ENTRY_OFS[0] * 4, res.r[0], px, py, pz, a0, a1, a2);
        level_accum<  64>(cbh + ENTRY_OFS[1] * 4, res.r[1], px, py, pz, a0, a1, a2);
        level_accum< 121>(cbh + ENTRY_OFS[2] * 4, res.r[2], px, py, pz, a0, a1, a2);
        level_accum< 196>(cbh + ENTRY_OFS[3] * 4, res.r[3], px, py, pz, a0, a1, a2);
        level_accum< 324>(cbh + ENTRY_OFS[4] * 4, res.r[4], px, py, pz, a0, a1, a2);
        level_accum< 529>(cbh + ENTRY_OFS[5] * 4, res.r[5], px, py, pz, a0, a1, a2);
        level_accum< 900>(cbh + ENTRY_OFS[6] * 4, res.r[6], px, py, pz, a0, a1, a2);
        level_accum<1024>(cbh + ENTRY_OFS[7] * 4, res.r[7], px, py, pz, a0, a1, a2);
        level_accum<1024>(cbh + ENTRY_OFS[8] * 4, res.r[8], px, py, pz, a0, a1, a2);
        level_accum<1024>(cbh + ENTRY_OFS[9] * 4, res.r[9], px, py, pz, a0, a1, a2);

        out[n * 3 + 0] = a0;
        out[n * 3 + 1] = a1;
        out[n * 3 + 2] = a2;
    }
}

extern "C" void kernel_launch(void* const* d_in, const int* in_sizes, int n_in,
                              void* d_out, int out_size, void* d_ws, size_t ws_size,
                              hipStream_t stream)
{
    const float* pts = (const float*)d_in[0];
    const int npts = in_sizes[0] / 3;

    // Replicate numpy's exact double-precision LOD computation (glibc libm).
    ResArr ra;
    const double b = exp((log(64.0) - log(6.0)) / 9.0);
    for (int l = 0; l < NLOD; ++l)
        ra.r[l] = (int)(1.0 + floor(6.0 * pow(b, (double)l)));

    // 512 blocks x 1024 thr: 2 blocks/CU (84 KB LDS), 32 waves/CU, 64 blocks/XCD;
    // 4-iteration grid-stride amortizes LDS staging over 4 points/thread.
    hashgrid_kernel<<<dim3(512), dim3(1024), 0, stream>>>(
        pts,
        (const float*)d_in[1], (const float*)d_in[2], (const float*)d_in[3],
        (const float*)d_in[4], (const float*)d_in[5], (const float*)d_in[6],
        (const float*)d_in[7], (const float*)d_in[8], (const float*)d_in[9],
        (const float*)d_in[10],
        (float*)d_out, npts, ra);
}